// Round 1
// baseline (128.965 us; speedup 1.0000x reference)
//
#include <hip/hip_runtime.h>
#include <hip/hip_bf16.h>

#define Bn 8192
#define Dn 256
#define MARGIN_F 0.5f

typedef short short8 __attribute__((ext_vector_type(8)));
typedef float floatx4 __attribute__((ext_vector_type(4)));

// RNE fp32 -> bf16 (inputs are finite; no NaN path needed)
__device__ inline unsigned short f2bf(float f) {
    unsigned int u = __float_as_uint(f);
    unsigned int r = (u + 0x7fffu + ((u >> 16) & 1u)) >> 16;
    return (unsigned short)r;
}

// ---------------- prep: cast to bf16, compute sq[i], init reduction buffers ----
__global__ __launch_bounds__(256) void prep_kernel(
        const float* __restrict__ emb, unsigned short* __restrict__ embB,
        float* __restrict__ sq, unsigned int* __restrict__ posb,
        unsigned int* __restrict__ negb) {
    const int w = threadIdx.x >> 6;
    const int lane = threadIdx.x & 63;
    const int row = blockIdx.x * 4 + w;   // grid = Bn/4 blocks of 256 (one wave/row)

    const float4 v = *(const float4*)(emb + (size_t)row * Dn + lane * 4);
    float ss = v.x * v.x + v.y * v.y + v.z * v.z + v.w * v.w;
    #pragma unroll
    for (int m = 32; m >= 1; m >>= 1) ss += __shfl_xor(ss, m);

    unsigned int lo = (unsigned int)f2bf(v.x) | ((unsigned int)f2bf(v.y) << 16);
    unsigned int hi = (unsigned int)f2bf(v.z) | ((unsigned int)f2bf(v.w) << 16);
    uint2 o; o.x = lo; o.y = hi;
    *(uint2*)(embB + (size_t)row * Dn + lane * 4) = o;

    if (lane == 0) {
        sq[row] = ss;
        posb[row] = 0u;            // "no positive seen" (any real encoded score > 0)
        negb[row] = 0xFFFFFFFFu;   // "no negative seen" (any real encoded score smaller)
    }
}

// ---------------- mine: X·X^T via MFMA with fused semi-hard reduction ----------
// block = 256 thr (4 waves). Block tile: 128 i-rows x 64 j-cols per iteration.
// Wave w handles i in [iBase, iBase+32). jsplit = 16 -> each block scans 512 j.
__global__ __launch_bounds__(256) void mine_kernel(
        const unsigned short* __restrict__ embB, const float* __restrict__ sq,
        const int* __restrict__ labels, unsigned int* __restrict__ posb,
        unsigned int* __restrict__ negb) {
    // pad 256 -> 264 bf16 (132 dwords == 4 mod 32): conflict-free b-frag reads
    __shared__ unsigned short sB[64][264];
    __shared__ int   sLab[64];
    __shared__ float sSq[64];

    const int tid  = threadIdx.x;
    const int w    = tid >> 6;
    const int lane = tid & 63;
    const int quad = lane >> 4;
    const int c    = lane & 15;

    const int iBase = blockIdx.x * 128 + w * 32;     // 64 i-blocks
    const int jSplitBase = blockIdx.y * (Bn / 16);   // 16 j-splits of 512

    // A fragments in registers for the whole j-loop: 2 m-subtiles x 8 k-steps
    // layout: A[m = lane&15][k = quad*8 + e], k-step stride 32
    short8 aFrag[2][8];
    #pragma unroll
    for (int m = 0; m < 2; ++m) {
        const unsigned short* ap = embB + (size_t)(iBase + m * 16 + c) * Dn + quad * 8;
        #pragma unroll
        for (int ks = 0; ks < 8; ++ks)
            aFrag[m][ks] = *(const short8*)(ap + ks * 32);
    }
    // labels for the rows this lane REDUCES (C/D layout rows: quad*4+r)
    int labI[2][4];
    #pragma unroll
    for (int m = 0; m < 2; ++m)
        #pragma unroll
        for (int r = 0; r < 4; ++r)
            labI[m][r] = labels[iBase + m * 16 + quad * 4 + r];

    float rpos[2][4], rneg[2][4];
    #pragma unroll
    for (int m = 0; m < 2; ++m)
        #pragma unroll
        for (int r = 0; r < 4; ++r) { rpos[m][r] = -1e30f; rneg[m][r] = 1e30f; }

    for (int jt = 0; jt < Bn / 16; jt += 64) {
        const int jBase = jSplitBase + jt;
        __syncthreads();  // protect sB/sLab/sSq from previous iteration's readers
        // stage 64 rows x 256 bf16 (32 KB), coalesced uint4
        #pragma unroll
        for (int it = 0; it < 8; ++it) {
            int g   = it * 256 + tid;
            int row = g >> 5;
            int ch  = g & 31;
            *(uint4*)(&sB[row][ch * 8]) =
                *(const uint4*)(embB + (size_t)(jBase + row) * Dn + ch * 8);
        }
        if (tid < 64) { sLab[tid] = labels[jBase + tid]; sSq[tid] = sq[jBase + tid]; }
        __syncthreads();

        #pragma unroll
        for (int n = 0; n < 4; ++n) {
            floatx4 acc0 = {0.f, 0.f, 0.f, 0.f};
            floatx4 acc1 = {0.f, 0.f, 0.f, 0.f};
            const unsigned short* bp = &sB[n * 16 + c][quad * 8];
            #pragma unroll
            for (int ks = 0; ks < 8; ++ks) {
                short8 bFrag = *(const short8*)(bp + ks * 32);
                acc0 = __builtin_amdgcn_mfma_f32_16x16x32_bf16(aFrag[0][ks], bFrag, acc0, 0, 0, 0);
                acc1 = __builtin_amdgcn_mfma_f32_16x16x32_bf16(aFrag[1][ks], bFrag, acc1, 0, 0, 0);
            }
            // fused epilogue: score s = sq_j - 2*dot; monotone proxy for dist
            const int   jg = jBase + n * 16 + c;
            const float sj = sSq[n * 16 + c];
            const int   lj = sLab[n * 16 + c];
            #pragma unroll
            for (int r = 0; r < 4; ++r) {
                float s0 = sj - 2.0f * acc0[r];
                float s1 = sj - 2.0f * acc1[r];
                int ig0 = iBase + quad * 4 + r;
                int ig1 = iBase + 16 + quad * 4 + r;
                bool same0 = (lj == labI[0][r]);
                bool same1 = (lj == labI[1][r]);
                if (same0 && ig0 != jg) rpos[0][r] = fmaxf(rpos[0][r], s0);
                if (!same0)             rneg[0][r] = fminf(rneg[0][r], s0);
                if (same1 && ig1 != jg) rpos[1][r] = fmaxf(rpos[1][r], s1);
                if (!same1)             rneg[1][r] = fminf(rneg[1][r], s1);
            }
        }
    }

    // reduce across the 16 lanes of each quad (masks 1,2,4,8 stay in-quad),
    // then merge to global. Encode s+4 in (2.9, 7.1): positive floats -> uint order.
    #pragma unroll
    for (int m = 0; m < 2; ++m)
        #pragma unroll
        for (int r = 0; r < 4; ++r) {
            float p = rpos[m][r], q = rneg[m][r];
            #pragma unroll
            for (int msk = 1; msk <= 8; msk <<= 1) {
                p = fmaxf(p, __shfl_xor(p, msk));
                q = fminf(q, __shfl_xor(q, msk));
            }
            if (c == 0) {
                int ig = iBase + m * 16 + quad * 4 + r;
                if (p > -1e29f) atomicMax(&posb[ig], __float_as_uint(p + 4.0f));
                if (q <  1e29f) atomicMin(&negb[ig], __float_as_uint(q + 4.0f));
            }
        }
}

// ---------------- finalize: decode, validity, mean --------------------------
__global__ __launch_bounds__(256) void finalize_kernel(
        const float* __restrict__ sq, const unsigned int* __restrict__ posb,
        const unsigned int* __restrict__ negb, float* __restrict__ out) {
    float total = 0.0f;
    float cnt = 0.0f;
    for (int i = threadIdx.x; i < Bn; i += 256) {
        unsigned int pb = posb[i], nb = negb[i];
        bool hp = (pb != 0u);
        bool hn = (nb != 0xFFFFFFFFu);
        float si  = sq[i];
        float dap = sqrtf(fmaxf(si + (__uint_as_float(pb) - 4.0f), 0.0f));
        float dan = sqrtf(fmaxf(si + (__uint_as_float(nb) - 4.0f), 0.0f));
        bool valid = hp && hn && (dan < dap + MARGIN_F);
        if (valid) {
            total += fmaxf(dap - dan + MARGIN_F, 0.0f);
            cnt += 1.0f;
        }
    }
    #pragma unroll
    for (int m = 32; m >= 1; m >>= 1) {
        total += __shfl_xor(total, m);
        cnt   += __shfl_xor(cnt, m);
    }
    __shared__ float sT[4], sC[4];
    int w = threadIdx.x >> 6, lane = threadIdx.x & 63;
    if (lane == 0) { sT[w] = total; sC[w] = cnt; }
    __syncthreads();
    if (threadIdx.x == 0) {
        float t = sT[0] + sT[1] + sT[2] + sT[3];
        float cc = sC[0] + sC[1] + sC[2] + sC[3];
        out[0] = (cc > 0.0f) ? t / cc : 0.0f;
    }
}

extern "C" void kernel_launch(void* const* d_in, const int* in_sizes, int n_in,
                              void* d_out, int out_size, void* d_ws, size_t ws_size,
                              hipStream_t stream) {
    const float* emb   = (const float*)d_in[0];
    const int*  labels = (const int*)d_in[1];
    float* out = (float*)d_out;

    char* ws = (char*)d_ws;
    unsigned short* embB = (unsigned short*)ws;                       // 4 MiB
    float*        sqv  = (float*)(ws + (size_t)Bn * Dn * 2);          // 32 KiB
    unsigned int* posb = (unsigned int*)(ws + (size_t)Bn * Dn * 2 + Bn * 4);
    unsigned int* negb = (unsigned int*)(ws + (size_t)Bn * Dn * 2 + Bn * 8);

    prep_kernel<<<Bn / 4, 256, 0, stream>>>(emb, embB, sqv, posb, negb);
    mine_kernel<<<dim3(64, 16), 256, 0, stream>>>(embB, sqv, labels, posb, negb);
    finalize_kernel<<<1, 256, 0, stream>>>(sqv, posb, negb, out);
}